// Round 10
// baseline (88.790 us; speedup 1.0000x reference)
//
#include <hip/hip_runtime.h>

// Chamfer distance via MFMA, B=4, N=M=8192, fp32 3D points — SINGLE PASS.
// d[n,m] = qsq[n] + tsq[m] - 2*q[n].t[m] via v_mfma_f32_32x32x16_bf16,
// split-precision bf16 operands (13 of 16 k-slots):
//   s0..s8 : per coord c: qh_c*(-2th_c), qh_c*(-2tl_c), ql_c*(-2th_c)
//   s9,s10 : qsq_h*1, qsq_l*1   s11,s12: 1*tsq_h, 1*tsq_l   s13..15: 0
// Round-10: each d-entry computed ONCE; dist1 = running row-min in regs
// (butterfly epilogue), dist2 = per-tile col-min via min3-tree over the
// SAME accvgpr-read values + shfl_xor(32) + plain ds_write to a per-wave
// private LDS region (NO LDS atomics — R4's mistake). Halves MFMA count
// and B-loads vs the two-pass R5. Global L2 loads (no staging, R7/R9
// lesson), #pragma unroll 4 (R5's best), no launch-bounds squeeze.

typedef short bf16x8 __attribute__((ext_vector_type(8)));
typedef float f32x16 __attribute__((ext_vector_type(16)));

constexpr int Bc  = 4;
constexpr int Nc  = 8192;
constexpr int NT  = Nc / 32;    // 256 tiles of 32 points
constexpr int SEG = 8;          // target segments
constexpr int TPS = NT / SEG;   // 32 target tiles per segment

__device__ inline unsigned short f2bf(float x) {
    unsigned u = __float_as_uint(x);
    unsigned r = (u + 0x7FFFu + ((u >> 16) & 1u)) >> 16;   // RNE
    return (unsigned short)r;
}
__device__ inline float bf2f(unsigned short h) {
    return __uint_as_float(((unsigned)h) << 16);
}
__device__ inline unsigned pack2(unsigned short lo, unsigned short hi) {
    return (unsigned)lo | ((unsigned)hi << 16);
}
__device__ inline float min3(float a, float b, float c) {
    return fminf(fminf(a, b), c);   // fuses to v_min3_f32
}

// Packs xyz1 -> q-form, xyz2 -> t-form fragments, AND inits out to +inf
// (tid range == out_size == 65536 exactly).
__global__ void pack_qt(const float* __restrict__ xyz1,
                        const float* __restrict__ xyz2,
                        uint4* __restrict__ qf, uint4* __restrict__ tf,
                        float* __restrict__ out) {
    const int tid  = blockIdx.x * 256 + threadIdx.x;   // [0, Bc*NT*64) = [0,65536)
    out[tid] = __uint_as_float(0x7F800000u);           // +inf
    const int lane = tid & 63;
    const int tile = (tid >> 6) & (NT - 1);
    const int b    = tid >> 14;
    const int pt   = tile * 32 + (lane & 31);
    const int kg   = lane >> 5;
    const unsigned short ONE = 0x3F80;

    {   // q-form from xyz1
        const float* p = xyz1 + ((size_t)b * Nc + pt) * 3;
        float x = p[0], y = p[1], z = p[2];
        float sq = x * x + y * y + z * z;
        unsigned short xh = f2bf(x), yh = f2bf(y), zh = f2bf(z);
        unsigned short xl = f2bf(x - bf2f(xh)), yl = f2bf(y - bf2f(yh)), zl = f2bf(z - bf2f(zh));
        unsigned short sh = f2bf(sq), sl = f2bf(sq - bf2f(sh));
        uint4 q;
        if (kg == 0) {
            q.x = pack2(xh, xh); q.y = pack2(xl, yh);
            q.z = pack2(yh, yl); q.w = pack2(zh, zh);
        } else {
            q.x = pack2(zl, sh); q.y = pack2(sl, ONE);
            q.z = pack2(ONE, 0); q.w = 0;
        }
        qf[tid] = q;
    }
    {   // t-form from xyz2
        const float* p = xyz2 + ((size_t)b * Nc + pt) * 3;
        float x = p[0], y = p[1], z = p[2];
        float sq = x * x + y * y + z * z;
        unsigned short xh = f2bf(x), yh = f2bf(y), zh = f2bf(z);
        unsigned short m2xh = f2bf(-2.0f * bf2f(xh));
        unsigned short m2yh = f2bf(-2.0f * bf2f(yh));
        unsigned short m2zh = f2bf(-2.0f * bf2f(zh));
        unsigned short m2xl = f2bf(-2.0f * (x - bf2f(xh)));
        unsigned short m2yl = f2bf(-2.0f * (y - bf2f(yh)));
        unsigned short m2zl = f2bf(-2.0f * (z - bf2f(zh)));
        unsigned short sh = f2bf(sq), sl = f2bf(sq - bf2f(sh));
        uint4 t;
        if (kg == 0) {
            t.x = pack2(m2xh, m2xl); t.y = pack2(m2xh, m2yh);
            t.z = pack2(m2yl, m2yh); t.w = pack2(m2zh, m2zl);
        } else {
            t.x = pack2(m2zh, ONE); t.y = pack2(ONE, sh);
            t.z = pack2(sl, 0);     t.w = 0;
        }
        tf[tid] = t;
    }
}

// Main: grid (NT/4, SEG, Bc), 256 threads = 4 waves. Wave w owns query tile
// n_tile = bx*4+w (32 xyz1 rows), sweeps TPS xyz2 tiles of segment `seg`.
// Both outputs from one d-matrix evaluation.
__global__ void chamfer_sp(
    const uint4* __restrict__ qf,   // [Bc*NT*64]
    const uint4* __restrict__ tf,   // [Bc*NT*64]
    float* __restrict__ out) {
    __shared__ float sMin[4][TPS][32];             // per-wave col-min, 16 KB
    const int tid = threadIdx.x, lane = tid & 63, wave = tid >> 6;
    const int b = blockIdx.z, seg = blockIdx.y;

    const int n_tile = blockIdx.x * 4 + wave;
    const bf16x8 av = __builtin_bit_cast(bf16x8,
        qf[((size_t)(b * NT + n_tile)) * 64 + lane]);
    f32x16 zc{};
    float rmin[16];
    #pragma unroll
    for (int r = 0; r < 16; ++r) rmin[r] = INFINITY;

    const uint4* bp = tf + ((size_t)(b * NT + seg * TPS)) * 64 + lane;

    #pragma unroll 4
    for (int mt = 0; mt < TPS; mt += 2) {
        const bf16x8 bv0 = __builtin_bit_cast(bf16x8, bp[(size_t)mt * 64]);
        const bf16x8 bv1 = __builtin_bit_cast(bf16x8, bp[(size_t)(mt + 1) * 64]);
        const f32x16 dA = __builtin_amdgcn_mfma_f32_32x32x16_bf16(av, bv0, zc, 0, 0, 0);
        const f32x16 dB = __builtin_amdgcn_mfma_f32_32x32x16_bf16(av, bv1, zc, 0, 0, 0);
        // dist1: running row-min (independent per r, v_min3).
        #pragma unroll
        for (int r = 0; r < 16; ++r)
            rmin[r] = min3(rmin[r], dA[r], dB[r]);
        // dist2: per-tile col-min over this lane's 16 rows (min3 tree),
        // combine lane-halves, store to this wave's private LDS slot.
        float a0 = min3(dA[0], dA[1], dA[2]),  a1 = min3(dA[3], dA[4], dA[5]);
        float a2 = min3(dA[6], dA[7], dA[8]),  a3 = min3(dA[9], dA[10], dA[11]);
        float a4 = min3(dA[12], dA[13], dA[14]);
        float cA = fminf(min3(a0, a1, a2), min3(a3, a4, dA[15]));
        float b0 = min3(dB[0], dB[1], dB[2]),  b1 = min3(dB[3], dB[4], dB[5]);
        float b2 = min3(dB[6], dB[7], dB[8]),  b3 = min3(dB[9], dB[10], dB[11]);
        float b4 = min3(dB[12], dB[13], dB[14]);
        float cB = fminf(min3(b0, b1, b2), min3(b3, b4, dB[15]));
        cA = fminf(cA, __shfl_xor(cA, 32));
        cB = fminf(cB, __shfl_xor(cB, 32));
        if (lane < 32) {
            sMin[wave][mt][lane]     = cA;
            sMin[wave][mt + 1][lane] = cB;
        }
    }

    // dist1 epilogue: butterfly over the 32 columns (lane bits 0..4);
    // lanes 0 and 32 hold row sets hi=0/1, write 16 atomics each.
    #pragma unroll
    for (int m = 1; m <= 16; m <<= 1)
        #pragma unroll
        for (int r = 0; r < 16; ++r)
            rmin[r] = fminf(rmin[r], __shfl_xor(rmin[r], m));
    if ((lane & 31) == 0) {
        const int hi = lane >> 5;
        unsigned* d1p = (unsigned*)out + (size_t)b * Nc + (size_t)n_tile * 32;
        #pragma unroll
        for (int r = 0; r < 16; ++r) {
            const int row = (r & 3) + 8 * (r >> 2) + 4 * hi;   // C/D layout (m74/m101)
            atomicMin(&d1p[row], __float_as_uint(fmaxf(rmin[r], 0.0f)));
        }
    }

    // dist2 epilogue: block-combine the 4 waves' private regions, one
    // global atomicMin per (tile,col) of this segment.
    __syncthreads();
    unsigned* d2p = (unsigned*)out + (size_t)Bc * Nc + (size_t)b * Nc
                  + (size_t)seg * (TPS * 32);
    #pragma unroll
    for (int i = 0; i < 4; ++i) {
        const int idx = tid + i * 256;                 // [0, 1024)
        const int mt = idx >> 5, col = idx & 31;
        float v = fminf(fminf(sMin[0][mt][col], sMin[1][mt][col]),
                        fminf(sMin[2][mt][col], sMin[3][mt][col]));
        atomicMin(&d2p[idx], __float_as_uint(fmaxf(v, 0.0f)));
    }
}

// ---- Fallback (ws too small): round-2 expansion kernel ----
constexpr int QPT = 2, TPB = 256;
__global__ void init_out_inf(float* __restrict__ out, int n) {
    int i = blockIdx.x * blockDim.x + threadIdx.x;
    int stride = gridDim.x * blockDim.x;
    for (; i < n; i += stride) out[i] = __uint_as_float(0x7F800000u);
}
__global__ void pack_pts(const float* __restrict__ src, float4* __restrict__ dst, int npts) {
    int i = blockIdx.x * blockDim.x + threadIdx.x;
    if (i < npts) {
        float x = src[3 * i], y = src[3 * i + 1], z = src[3 * i + 2];
        dst[i] = make_float4(x, y, z, x * x + y * y + z * z);
    }
}
__global__ __launch_bounds__(TPB, 8) void chamfer_fb(
    const float* __restrict__ xyz1, const float* __restrict__ xyz2,
    const float4* __restrict__ p1, const float4* __restrict__ p2,
    float* __restrict__ out) {
    const int z = blockIdx.z, dir = z >> 2, b = z & 3, seg = blockIdx.y;
    const float*  qry  = dir ? xyz2 : xyz1;
    const float4* tgt4 = dir ? p1 : p2;
    float* o = out + (size_t)dir * Bc * Nc + (size_t)b * Nc;
    const int q0 = blockIdx.x * (TPB * QPT) + threadIdx.x;
    float m2x[QPT], m2y[QPT], m2z[QPT], qsq[QPT];
    #pragma unroll
    for (int j = 0; j < QPT; ++j) {
        const float* qp = qry + ((size_t)b * Nc + q0 + j * TPB) * 3;
        float x = qp[0], y = qp[1], zz = qp[2];
        m2x[j] = -2.f * x; m2y[j] = -2.f * y; m2z[j] = -2.f * zz;
        qsq[j] = x * x + y * y + zz * zz;
    }
    constexpr int seg_pts = Nc / 16;
    const float4* t = tgt4 + (size_t)b * Nc + (size_t)seg * seg_pts;
    float mn0[QPT], mn1[QPT];
    #pragma unroll
    for (int j = 0; j < QPT; ++j) { mn0[j] = INFINITY; mn1[j] = INFINITY; }
    #pragma unroll 4
    for (int i = 0; i < seg_pts; i += 2) {
        const float4 t0 = t[i], t1 = t[i + 1];
        #pragma unroll
        for (int j = 0; j < QPT; ++j) {
            mn0[j] = fminf(mn0[j], fmaf(m2x[j], t0.x, fmaf(m2y[j], t0.y, fmaf(m2z[j], t0.z, t0.w))));
            mn1[j] = fminf(mn1[j], fmaf(m2x[j], t1.x, fmaf(m2y[j], t1.y, fmaf(m2z[j], t1.z, t1.w))));
        }
    }
    #pragma unroll
    for (int j = 0; j < QPT; ++j) {
        float d = fmaxf(qsq[j] + fminf(mn0[j], mn1[j]), 0.f);
        atomicMin((unsigned*)(o + q0 + j * TPB), __float_as_uint(d));
    }
}

extern "C" void kernel_launch(void* const* d_in, const int* in_sizes, int n_in,
                              void* d_out, int out_size, void* d_ws, size_t ws_size,
                              hipStream_t stream) {
    const float* xyz1 = (const float*)d_in[0];
    const float* xyz2 = (const float*)d_in[1];
    float* out = (float*)d_out;

    const size_t FR = (size_t)Bc * NT * 64;               // 65536 uint4 per array
    const size_t need = 2 * FR * sizeof(uint4);           // 2 MiB (qf + tf)

    if (ws_size >= need) {
        uint4* qf = (uint4*)d_ws;          // [FR]
        uint4* tf = qf + FR;               // [FR]
        pack_qt<<<dim3(FR / 256), dim3(256), 0, stream>>>(xyz1, xyz2, qf, tf, out);
        dim3 grid(NT / 4, SEG, Bc);                       // 64 x 8 x 4 = 2048 blocks
        chamfer_sp<<<grid, dim3(256), 0, stream>>>(qf, tf, out);
    } else if (ws_size >= 2 * (size_t)Bc * Nc * sizeof(float4)) {
        init_out_inf<<<dim3(64), dim3(256), 0, stream>>>(out, out_size);
        float4* p1 = (float4*)d_ws;
        float4* p2 = p1 + Bc * Nc;
        pack_pts<<<dim3(Bc * Nc / 256), dim3(256), 0, stream>>>(xyz1, p1, Bc * Nc);
        pack_pts<<<dim3(Bc * Nc / 256), dim3(256), 0, stream>>>(xyz2, p2, Bc * Nc);
        dim3 grid(Nc / (TPB * QPT), 16, 2 * Bc);
        chamfer_fb<<<grid, dim3(TPB), 0, stream>>>(xyz1, xyz2, p1, p2, out);
    }
}

// Round 11
// 43.483 us; speedup vs baseline: 2.0420x; 2.0420x over previous
//
#include <hip/hip_runtime.h>

// Chamfer distance via MFMA, B=4, N=M=8192, fp32 3D points — SINGLE PASS.
// d[n,m] = qsq[n] + tsq[m] - 2*q[n].t[m] via v_mfma_f32_32x32x16_bf16,
// split-precision bf16 operands (13 of 16 k-slots):
//   s0..s8 : per coord c: qh_c*(-2th_c), qh_c*(-2tl_c), ql_c*(-2th_c)
//   s9,s10 : qsq_h*1, qsq_l*1   s11,s12: 1*tsq_h, 1*tsq_l   s13..15: 0
// Round-11 = R4 single-pass + three proven fixes:
//  * dist2 col-min: 8-op min3 tree + shfl_xor(32) + PLAIN ds_write to a
//    per-wave private LDS region (R4's LDS atomicMin chain removed).
//  * ONE tile per iteration, #pragma unroll 2 -> max 2 acc-tiles in flight.
//    (R10's unroll-4 x tile-pairs spilled: 273 MB scratch traffic.)
//  * init fused into pack (R9): one 0.5us prep kernel, 2 launches total.

typedef short bf16x8 __attribute__((ext_vector_type(8)));
typedef float f32x16 __attribute__((ext_vector_type(16)));

constexpr int Bc  = 4;
constexpr int Nc  = 8192;
constexpr int NT  = Nc / 32;    // 256 tiles of 32 points
constexpr int SEG = 8;          // target segments
constexpr int TPS = NT / SEG;   // 32 target tiles per segment

__device__ inline unsigned short f2bf(float x) {
    unsigned u = __float_as_uint(x);
    unsigned r = (u + 0x7FFFu + ((u >> 16) & 1u)) >> 16;   // RNE
    return (unsigned short)r;
}
__device__ inline float bf2f(unsigned short h) {
    return __uint_as_float(((unsigned)h) << 16);
}
__device__ inline unsigned pack2(unsigned short lo, unsigned short hi) {
    return (unsigned)lo | ((unsigned)hi << 16);
}
__device__ inline float min3(float a, float b, float c) {
    return fminf(fminf(a, b), c);   // fuses to v_min3_f32
}

// Packs xyz1 -> q-form, xyz2 -> t-form fragments, AND inits out to +inf
// (tid range == out_size == 65536 exactly).
__global__ void pack_qt(const float* __restrict__ xyz1,
                        const float* __restrict__ xyz2,
                        uint4* __restrict__ qf, uint4* __restrict__ tf,
                        float* __restrict__ out) {
    const int tid  = blockIdx.x * 256 + threadIdx.x;   // [0, Bc*NT*64) = [0,65536)
    out[tid] = __uint_as_float(0x7F800000u);           // +inf
    const int lane = tid & 63;
    const int tile = (tid >> 6) & (NT - 1);
    const int b    = tid >> 14;
    const int pt   = tile * 32 + (lane & 31);
    const int kg   = lane >> 5;
    const unsigned short ONE = 0x3F80;

    {   // q-form from xyz1
        const float* p = xyz1 + ((size_t)b * Nc + pt) * 3;
        float x = p[0], y = p[1], z = p[2];
        float sq = x * x + y * y + z * z;
        unsigned short xh = f2bf(x), yh = f2bf(y), zh = f2bf(z);
        unsigned short xl = f2bf(x - bf2f(xh)), yl = f2bf(y - bf2f(yh)), zl = f2bf(z - bf2f(zh));
        unsigned short sh = f2bf(sq), sl = f2bf(sq - bf2f(sh));
        uint4 q;
        if (kg == 0) {
            q.x = pack2(xh, xh); q.y = pack2(xl, yh);
            q.z = pack2(yh, yl); q.w = pack2(zh, zh);
        } else {
            q.x = pack2(zl, sh); q.y = pack2(sl, ONE);
            q.z = pack2(ONE, 0); q.w = 0;
        }
        qf[tid] = q;
    }
    {   // t-form from xyz2
        const float* p = xyz2 + ((size_t)b * Nc + pt) * 3;
        float x = p[0], y = p[1], z = p[2];
        float sq = x * x + y * y + z * z;
        unsigned short xh = f2bf(x), yh = f2bf(y), zh = f2bf(z);
        unsigned short m2xh = f2bf(-2.0f * bf2f(xh));
        unsigned short m2yh = f2bf(-2.0f * bf2f(yh));
        unsigned short m2zh = f2bf(-2.0f * bf2f(zh));
        unsigned short m2xl = f2bf(-2.0f * (x - bf2f(xh)));
        unsigned short m2yl = f2bf(-2.0f * (y - bf2f(yh)));
        unsigned short m2zl = f2bf(-2.0f * (z - bf2f(zh)));
        unsigned short sh = f2bf(sq), sl = f2bf(sq - bf2f(sh));
        uint4 t;
        if (kg == 0) {
            t.x = pack2(m2xh, m2xl); t.y = pack2(m2xh, m2yh);
            t.z = pack2(m2yl, m2yh); t.w = pack2(m2zh, m2zl);
        } else {
            t.x = pack2(m2zh, ONE); t.y = pack2(ONE, sh);
            t.z = pack2(sl, 0);     t.w = 0;
        }
        tf[tid] = t;
    }
}

// Main: grid (NT/4, SEG, Bc), 256 threads = 4 waves. Wave w owns query tile
// n_tile = bx*4+w (32 xyz1 rows), sweeps TPS xyz2 tiles of segment `seg`.
// Both outputs from one d-matrix evaluation; ONE tile per iteration.
__global__ void chamfer_sp(
    const uint4* __restrict__ qf,   // [Bc*NT*64]
    const uint4* __restrict__ tf,   // [Bc*NT*64]
    float* __restrict__ out) {
    __shared__ float sMin[4][TPS][32];             // per-wave col-min, 16 KB
    const int tid = threadIdx.x, lane = tid & 63, wave = tid >> 6;
    const int b = blockIdx.z, seg = blockIdx.y;

    const int n_tile = blockIdx.x * 4 + wave;
    const bf16x8 av = __builtin_bit_cast(bf16x8,
        qf[((size_t)(b * NT + n_tile)) * 64 + lane]);
    f32x16 zc{};
    float rmin[16];
    #pragma unroll
    for (int r = 0; r < 16; ++r) rmin[r] = INFINITY;

    const uint4* bp = tf + ((size_t)(b * NT + seg * TPS)) * 64 + lane;

    #pragma unroll 2
    for (int mt = 0; mt < TPS; ++mt) {
        const bf16x8 bv = __builtin_bit_cast(bf16x8, bp[(size_t)mt * 64]);
        const f32x16 d = __builtin_amdgcn_mfma_f32_32x32x16_bf16(av, bv, zc, 0, 0, 0);
        // dist1: running row-min (independent per r).
        #pragma unroll
        for (int r = 0; r < 16; ++r) rmin[r] = fminf(rmin[r], d[r]);
        // dist2: col-min over this lane's 16 rows (min3 tree, 8 ops),
        // merge lane-halves, plain store to this wave's private LDS slot.
        float a0 = min3(d[0],  d[1],  d[2]);
        float a1 = min3(d[3],  d[4],  d[5]);
        float a2 = min3(d[6],  d[7],  d[8]);
        float a3 = min3(d[9],  d[10], d[11]);
        float a4 = min3(d[12], d[13], d[14]);
        float c  = fminf(min3(a0, a1, a2), min3(a3, a4, d[15]));
        c = fminf(c, __shfl_xor(c, 32));
        if (lane < 32) sMin[wave][mt][lane] = c;
    }

    // dist1 epilogue: butterfly over the 32 columns (lane bits 0..4);
    // lanes 0 and 32 hold row sets hi=0/1, write 16 atomics each.
    #pragma unroll
    for (int m = 1; m <= 16; m <<= 1)
        #pragma unroll
        for (int r = 0; r < 16; ++r)
            rmin[r] = fminf(rmin[r], __shfl_xor(rmin[r], m));
    if ((lane & 31) == 0) {
        const int hi = lane >> 5;
        unsigned* d1p = (unsigned*)out + (size_t)b * Nc + (size_t)n_tile * 32;
        #pragma unroll
        for (int r = 0; r < 16; ++r) {
            const int row = (r & 3) + 8 * (r >> 2) + 4 * hi;   // C/D layout (m74/m101)
            atomicMin(&d1p[row], __float_as_uint(fmaxf(rmin[r], 0.0f)));
        }
    }

    // dist2 epilogue: block-combine the 4 waves' private regions, one
    // global atomicMin per (tile,col) of this segment.
    __syncthreads();
    unsigned* d2p = (unsigned*)out + (size_t)Bc * Nc + (size_t)b * Nc
                  + (size_t)seg * (TPS * 32);
    #pragma unroll
    for (int i = 0; i < 4; ++i) {
        const int idx = tid + i * 256;                 // [0, 1024)
        const int mt = idx >> 5, col = idx & 31;
        float v = fminf(fminf(sMin[0][mt][col], sMin[1][mt][col]),
                        fminf(sMin[2][mt][col], sMin[3][mt][col]));
        atomicMin(&d2p[idx], __float_as_uint(fmaxf(v, 0.0f)));
    }
}

// ---- Fallback (ws too small): round-2 expansion kernel ----
constexpr int QPT = 2, TPB = 256;
__global__ void init_out_inf(float* __restrict__ out, int n) {
    int i = blockIdx.x * blockDim.x + threadIdx.x;
    int stride = gridDim.x * blockDim.x;
    for (; i < n; i += stride) out[i] = __uint_as_float(0x7F800000u);
}
__global__ void pack_pts(const float* __restrict__ src, float4* __restrict__ dst, int npts) {
    int i = blockIdx.x * blockDim.x + threadIdx.x;
    if (i < npts) {
        float x = src[3 * i], y = src[3 * i + 1], z = src[3 * i + 2];
        dst[i] = make_float4(x, y, z, x * x + y * y + z * z);
    }
}
__global__ __launch_bounds__(TPB, 8) void chamfer_fb(
    const float* __restrict__ xyz1, const float* __restrict__ xyz2,
    const float4* __restrict__ p1, const float4* __restrict__ p2,
    float* __restrict__ out) {
    const int z = blockIdx.z, dir = z >> 2, b = z & 3, seg = blockIdx.y;
    const float*  qry  = dir ? xyz2 : xyz1;
    const float4* tgt4 = dir ? p1 : p2;
    float* o = out + (size_t)dir * Bc * Nc + (size_t)b * Nc;
    const int q0 = blockIdx.x * (TPB * QPT) + threadIdx.x;
    float m2x[QPT], m2y[QPT], m2z[QPT], qsq[QPT];
    #pragma unroll
    for (int j = 0; j < QPT; ++j) {
        const float* qp = qry + ((size_t)b * Nc + q0 + j * TPB) * 3;
        float x = qp[0], y = qp[1], zz = qp[2];
        m2x[j] = -2.f * x; m2y[j] = -2.f * y; m2z[j] = -2.f * zz;
        qsq[j] = x * x + y * y + zz * zz;
    }
    constexpr int seg_pts = Nc / 16;
    const float4* t = tgt4 + (size_t)b * Nc + (size_t)seg * seg_pts;
    float mn0[QPT], mn1[QPT];
    #pragma unroll
    for (int j = 0; j < QPT; ++j) { mn0[j] = INFINITY; mn1[j] = INFINITY; }
    #pragma unroll 4
    for (int i = 0; i < seg_pts; i += 2) {
        const float4 t0 = t[i], t1 = t[i + 1];
        #pragma unroll
        for (int j = 0; j < QPT; ++j) {
            mn0[j] = fminf(mn0[j], fmaf(m2x[j], t0.x, fmaf(m2y[j], t0.y, fmaf(m2z[j], t0.z, t0.w))));
            mn1[j] = fminf(mn1[j], fmaf(m2x[j], t1.x, fmaf(m2y[j], t1.y, fmaf(m2z[j], t1.z, t1.w))));
        }
    }
    #pragma unroll
    for (int j = 0; j < QPT; ++j) {
        float d = fmaxf(qsq[j] + fminf(mn0[j], mn1[j]), 0.f);
        atomicMin((unsigned*)(o + q0 + j * TPB), __float_as_uint(d));
    }
}

extern "C" void kernel_launch(void* const* d_in, const int* in_sizes, int n_in,
                              void* d_out, int out_size, void* d_ws, size_t ws_size,
                              hipStream_t stream) {
    const float* xyz1 = (const float*)d_in[0];
    const float* xyz2 = (const float*)d_in[1];
    float* out = (float*)d_out;

    const size_t FR = (size_t)Bc * NT * 64;               // 65536 uint4 per array
    const size_t need = 2 * FR * sizeof(uint4);           // 2 MiB (qf + tf)

    if (ws_size >= need) {
        uint4* qf = (uint4*)d_ws;          // [FR]
        uint4* tf = qf + FR;               // [FR]
        pack_qt<<<dim3(FR / 256), dim3(256), 0, stream>>>(xyz1, xyz2, qf, tf, out);
        dim3 grid(NT / 4, SEG, Bc);                       // 64 x 8 x 4 = 2048 blocks
        chamfer_sp<<<grid, dim3(256), 0, stream>>>(qf, tf, out);
    } else if (ws_size >= 2 * (size_t)Bc * Nc * sizeof(float4)) {
        init_out_inf<<<dim3(64), dim3(256), 0, stream>>>(out, out_size);
        float4* p1 = (float4*)d_ws;
        float4* p2 = p1 + Bc * Nc;
        pack_pts<<<dim3(Bc * Nc / 256), dim3(256), 0, stream>>>(xyz1, p1, Bc * Nc);
        pack_pts<<<dim3(Bc * Nc / 256), dim3(256), 0, stream>>>(xyz2, p2, Bc * Nc);
        dim3 grid(Nc / (TPB * QPT), 16, 2 * Bc);
        chamfer_fb<<<grid, dim3(TPB), 0, stream>>>(xyz1, xyz2, p1, p2, out);
    }
}

// Round 12
// 36.656 us; speedup vs baseline: 2.4222x; 1.1862x over previous
//
#include <hip/hip_runtime.h>

// Chamfer distance via MFMA, B=4, N=M=8192, fp32 3D points — SINGLE PASS.
// d[n,m] = qsq[n] + tsq[m] - 2*q[n].t[m] via v_mfma_f32_32x32x16_bf16,
// split-precision bf16 operands (13 of 16 k-slots):
//   s0..s8 : per coord c: qh_c*(-2th_c), qh_c*(-2tl_c), ql_c*(-2th_c)
//   s9,s10 : qsq_h*1, qsq_l*1   s11,s12: 1*tsq_h, 1*tsq_l   s13..15: 0
// Round-12 = R11 + paired-tile body: TWO B-tiles per iteration so dist1
// folds as rmin = min3(rmin, dA[r], dB[r]) (16 min3 per 2 tiles instead of
// 32 fmin). #pragma unroll 1 caps live accumulators at 2 tiles (~100 VGPR)
// — R10's 273MB spill came from unroll-4 stacking 8 tiles, not the pairing.
// dist2 per tile: 8-op min3 tree + shfl_xor(32) + plain ds_write to a
// per-wave private LDS region; block-combine + global atomicMin drain.

typedef short bf16x8 __attribute__((ext_vector_type(8)));
typedef float f32x16 __attribute__((ext_vector_type(16)));

constexpr int Bc  = 4;
constexpr int Nc  = 8192;
constexpr int NT  = Nc / 32;    // 256 tiles of 32 points
constexpr int SEG = 8;          // target segments
constexpr int TPS = NT / SEG;   // 32 target tiles per segment

__device__ inline unsigned short f2bf(float x) {
    unsigned u = __float_as_uint(x);
    unsigned r = (u + 0x7FFFu + ((u >> 16) & 1u)) >> 16;   // RNE
    return (unsigned short)r;
}
__device__ inline float bf2f(unsigned short h) {
    return __uint_as_float(((unsigned)h) << 16);
}
__device__ inline unsigned pack2(unsigned short lo, unsigned short hi) {
    return (unsigned)lo | ((unsigned)hi << 16);
}
__device__ inline float min3(float a, float b, float c) {
    return fminf(fminf(a, b), c);   // fuses to v_min3_f32
}

// Packs xyz1 -> q-form, xyz2 -> t-form fragments, AND inits out to +inf
// (tid range == out_size == 65536 exactly).
__global__ void pack_qt(const float* __restrict__ xyz1,
                        const float* __restrict__ xyz2,
                        uint4* __restrict__ qf, uint4* __restrict__ tf,
                        float* __restrict__ out) {
    const int tid  = blockIdx.x * 256 + threadIdx.x;   // [0, Bc*NT*64) = [0,65536)
    out[tid] = __uint_as_float(0x7F800000u);           // +inf
    const int lane = tid & 63;
    const int tile = (tid >> 6) & (NT - 1);
    const int b    = tid >> 14;
    const int pt   = tile * 32 + (lane & 31);
    const int kg   = lane >> 5;
    const unsigned short ONE = 0x3F80;

    {   // q-form from xyz1
        const float* p = xyz1 + ((size_t)b * Nc + pt) * 3;
        float x = p[0], y = p[1], z = p[2];
        float sq = x * x + y * y + z * z;
        unsigned short xh = f2bf(x), yh = f2bf(y), zh = f2bf(z);
        unsigned short xl = f2bf(x - bf2f(xh)), yl = f2bf(y - bf2f(yh)), zl = f2bf(z - bf2f(zh));
        unsigned short sh = f2bf(sq), sl = f2bf(sq - bf2f(sh));
        uint4 q;
        if (kg == 0) {
            q.x = pack2(xh, xh); q.y = pack2(xl, yh);
            q.z = pack2(yh, yl); q.w = pack2(zh, zh);
        } else {
            q.x = pack2(zl, sh); q.y = pack2(sl, ONE);
            q.z = pack2(ONE, 0); q.w = 0;
        }
        qf[tid] = q;
    }
    {   // t-form from xyz2
        const float* p = xyz2 + ((size_t)b * Nc + pt) * 3;
        float x = p[0], y = p[1], z = p[2];
        float sq = x * x + y * y + z * z;
        unsigned short xh = f2bf(x), yh = f2bf(y), zh = f2bf(z);
        unsigned short m2xh = f2bf(-2.0f * bf2f(xh));
        unsigned short m2yh = f2bf(-2.0f * bf2f(yh));
        unsigned short m2zh = f2bf(-2.0f * bf2f(zh));
        unsigned short m2xl = f2bf(-2.0f * (x - bf2f(xh)));
        unsigned short m2yl = f2bf(-2.0f * (y - bf2f(yh)));
        unsigned short m2zl = f2bf(-2.0f * (z - bf2f(zh)));
        unsigned short sh = f2bf(sq), sl = f2bf(sq - bf2f(sh));
        uint4 t;
        if (kg == 0) {
            t.x = pack2(m2xh, m2xl); t.y = pack2(m2xh, m2yh);
            t.z = pack2(m2yl, m2yh); t.w = pack2(m2zh, m2zl);
        } else {
            t.x = pack2(m2zh, ONE); t.y = pack2(ONE, sh);
            t.z = pack2(sl, 0);     t.w = 0;
        }
        tf[tid] = t;
    }
}

// Main: grid (NT/4, SEG, Bc), 256 threads = 4 waves. Wave w owns query tile
// n_tile = bx*4+w (32 xyz1 rows), sweeps TPS xyz2 tiles of segment `seg`.
// Both outputs from one d-matrix evaluation; TWO tiles per iteration.
__global__ void chamfer_sp(
    const uint4* __restrict__ qf,   // [Bc*NT*64]
    const uint4* __restrict__ tf,   // [Bc*NT*64]
    float* __restrict__ out) {
    __shared__ float sMin[4][TPS][32];             // per-wave col-min, 16 KB
    const int tid = threadIdx.x, lane = tid & 63, wave = tid >> 6;
    const int b = blockIdx.z, seg = blockIdx.y;

    const int n_tile = blockIdx.x * 4 + wave;
    const bf16x8 av = __builtin_bit_cast(bf16x8,
        qf[((size_t)(b * NT + n_tile)) * 64 + lane]);
    f32x16 zc{};
    float rmin[16];
    #pragma unroll
    for (int r = 0; r < 16; ++r) rmin[r] = INFINITY;

    const uint4* bp = tf + ((size_t)(b * NT + seg * TPS)) * 64 + lane;

    #pragma unroll 1
    for (int mt = 0; mt < TPS; mt += 2) {
        const bf16x8 bv0 = __builtin_bit_cast(bf16x8, bp[(size_t)mt * 64]);
        const bf16x8 bv1 = __builtin_bit_cast(bf16x8, bp[(size_t)(mt + 1) * 64]);
        const f32x16 dA = __builtin_amdgcn_mfma_f32_32x32x16_bf16(av, bv0, zc, 0, 0, 0);
        const f32x16 dB = __builtin_amdgcn_mfma_f32_32x32x16_bf16(av, bv1, zc, 0, 0, 0);
        // dist1: fold both tiles in one min3 per register.
        #pragma unroll
        for (int r = 0; r < 16; ++r)
            rmin[r] = min3(rmin[r], dA[r], dB[r]);
        // dist2: per-tile col-min over this lane's 16 rows (min3 tree),
        // merge lane-halves, plain store to this wave's private LDS slot.
        float a0 = min3(dA[0],  dA[1],  dA[2]);
        float a1 = min3(dA[3],  dA[4],  dA[5]);
        float a2 = min3(dA[6],  dA[7],  dA[8]);
        float a3 = min3(dA[9],  dA[10], dA[11]);
        float a4 = min3(dA[12], dA[13], dA[14]);
        float cA = fminf(min3(a0, a1, a2), min3(a3, a4, dA[15]));
        float b0 = min3(dB[0],  dB[1],  dB[2]);
        float b1 = min3(dB[3],  dB[4],  dB[5]);
        float b2 = min3(dB[6],  dB[7],  dB[8]);
        float b3 = min3(dB[9],  dB[10], dB[11]);
        float b4 = min3(dB[12], dB[13], dB[14]);
        float cB = fminf(min3(b0, b1, b2), min3(b3, b4, dB[15]));
        cA = fminf(cA, __shfl_xor(cA, 32));
        cB = fminf(cB, __shfl_xor(cB, 32));
        if (lane < 32) {
            sMin[wave][mt][lane]     = cA;
            sMin[wave][mt + 1][lane] = cB;
        }
    }

    // dist1 epilogue: butterfly over the 32 columns (lane bits 0..4);
    // lanes 0 and 32 hold row sets hi=0/1, write 16 atomics each.
    #pragma unroll
    for (int m = 1; m <= 16; m <<= 1)
        #pragma unroll
        for (int r = 0; r < 16; ++r)
            rmin[r] = fminf(rmin[r], __shfl_xor(rmin[r], m));
    if ((lane & 31) == 0) {
        const int hi = lane >> 5;
        unsigned* d1p = (unsigned*)out + (size_t)b * Nc + (size_t)n_tile * 32;
        #pragma unroll
        for (int r = 0; r < 16; ++r) {
            const int row = (r & 3) + 8 * (r >> 2) + 4 * hi;   // C/D layout (m74/m101)
            atomicMin(&d1p[row], __float_as_uint(fmaxf(rmin[r], 0.0f)));
        }
    }

    // dist2 epilogue: block-combine the 4 waves' private regions, one
    // global atomicMin per (tile,col) of this segment.
    __syncthreads();
    unsigned* d2p = (unsigned*)out + (size_t)Bc * Nc + (size_t)b * Nc
                  + (size_t)seg * (TPS * 32);
    #pragma unroll
    for (int i = 0; i < 4; ++i) {
        const int idx = tid + i * 256;                 // [0, 1024)
        const int mt = idx >> 5, col = idx & 31;
        float v = fminf(fminf(sMin[0][mt][col], sMin[1][mt][col]),
                        fminf(sMin[2][mt][col], sMin[3][mt][col]));
        atomicMin(&d2p[idx], __float_as_uint(fmaxf(v, 0.0f)));
    }
}

// ---- Fallback (ws too small): round-2 expansion kernel ----
constexpr int QPT = 2, TPB = 256;
__global__ void init_out_inf(float* __restrict__ out, int n) {
    int i = blockIdx.x * blockDim.x + threadIdx.x;
    int stride = gridDim.x * blockDim.x;
    for (; i < n; i += stride) out[i] = __uint_as_float(0x7F800000u);
}
__global__ void pack_pts(const float* __restrict__ src, float4* __restrict__ dst, int npts) {
    int i = blockIdx.x * blockDim.x + threadIdx.x;
    if (i < npts) {
        float x = src[3 * i], y = src[3 * i + 1], z = src[3 * i + 2];
        dst[i] = make_float4(x, y, z, x * x + y * y + z * z);
    }
}
__global__ __launch_bounds__(TPB, 8) void chamfer_fb(
    const float* __restrict__ xyz1, const float* __restrict__ xyz2,
    const float4* __restrict__ p1, const float4* __restrict__ p2,
    float* __restrict__ out) {
    const int z = blockIdx.z, dir = z >> 2, b = z & 3, seg = blockIdx.y;
    const float*  qry  = dir ? xyz2 : xyz1;
    const float4* tgt4 = dir ? p1 : p2;
    float* o = out + (size_t)dir * Bc * Nc + (size_t)b * Nc;
    const int q0 = blockIdx.x * (TPB * QPT) + threadIdx.x;
    float m2x[QPT], m2y[QPT], m2z[QPT], qsq[QPT];
    #pragma unroll
    for (int j = 0; j < QPT; ++j) {
        const float* qp = qry + ((size_t)b * Nc + q0 + j * TPB) * 3;
        float x = qp[0], y = qp[1], zz = qp[2];
        m2x[j] = -2.f * x; m2y[j] = -2.f * y; m2z[j] = -2.f * zz;
        qsq[j] = x * x + y * y + zz * zz;
    }
    constexpr int seg_pts = Nc / 16;
    const float4* t = tgt4 + (size_t)b * Nc + (size_t)seg * seg_pts;
    float mn0[QPT], mn1[QPT];
    #pragma unroll
    for (int j = 0; j < QPT; ++j) { mn0[j] = INFINITY; mn1[j] = INFINITY; }
    #pragma unroll 4
    for (int i = 0; i < seg_pts; i += 2) {
        const float4 t0 = t[i], t1 = t[i + 1];
        #pragma unroll
        for (int j = 0; j < QPT; ++j) {
            mn0[j] = fminf(mn0[j], fmaf(m2x[j], t0.x, fmaf(m2y[j], t0.y, fmaf(m2z[j], t0.z, t0.w))));
            mn1[j] = fminf(mn1[j], fmaf(m2x[j], t1.x, fmaf(m2y[j], t1.y, fmaf(m2z[j], t1.z, t1.w))));
        }
    }
    #pragma unroll
    for (int j = 0; j < QPT; ++j) {
        float d = fmaxf(qsq[j] + fminf(mn0[j], mn1[j]), 0.f);
        atomicMin((unsigned*)(o + q0 + j * TPB), __float_as_uint(d));
    }
}

extern "C" void kernel_launch(void* const* d_in, const int* in_sizes, int n_in,
                              void* d_out, int out_size, void* d_ws, size_t ws_size,
                              hipStream_t stream) {
    const float* xyz1 = (const float*)d_in[0];
    const float* xyz2 = (const float*)d_in[1];
    float* out = (float*)d_out;

    const size_t FR = (size_t)Bc * NT * 64;               // 65536 uint4 per array
    const size_t need = 2 * FR * sizeof(uint4);           // 2 MiB (qf + tf)

    if (ws_size >= need) {
        uint4* qf = (uint4*)d_ws;          // [FR]
        uint4* tf = qf + FR;               // [FR]
        pack_qt<<<dim3(FR / 256), dim3(256), 0, stream>>>(xyz1, xyz2, qf, tf, out);
        dim3 grid(NT / 4, SEG, Bc);                       // 64 x 8 x 4 = 2048 blocks
        chamfer_sp<<<grid, dim3(256), 0, stream>>>(qf, tf, out);
    } else if (ws_size >= 2 * (size_t)Bc * Nc * sizeof(float4)) {
        init_out_inf<<<dim3(64), dim3(256), 0, stream>>>(out, out_size);
        float4* p1 = (float4*)d_ws;
        float4* p2 = p1 + Bc * Nc;
        pack_pts<<<dim3(Bc * Nc / 256), dim3(256), 0, stream>>>(xyz1, p1, Bc * Nc);
        pack_pts<<<dim3(Bc * Nc / 256), dim3(256), 0, stream>>>(xyz2, p2, Bc * Nc);
        dim3 grid(Nc / (TPB * QPT), 16, 2 * Bc);
        chamfer_fb<<<grid, dim3(TPB), 0, stream>>>(xyz1, xyz2, p1, p2, out);
    }
}